// Round 2
// baseline (480.374 us; speedup 1.0000x reference)
//
#include <hip/hip_runtime.h>
#include <hip/hip_fp16.h>

#define MDIM 8192   // B*S = 4*2048
#define NDIM 4096   // OUT
#define KDIM 4096   // IN

typedef unsigned short u16;
typedef __bf16 bf16x8 __attribute__((ext_vector_type(8)));
typedef float f32x4 __attribute__((ext_vector_type(4)));

static __device__ __forceinline__ u16 f2bf(float f) {
  union { float f; unsigned u; } v; v.f = f;
  unsigned r = v.u + 0x7fffu + ((v.u >> 16) & 1u);  // round-to-nearest-even
  return (u16)(r >> 16);
}

// scales/zeros may arrive as fp16 (reference dtype) or promoted to fp32 by the
// harness. Detect from the first 4 bytes: fp32 storage puts the exponent bits
// of a value in [1e-4, 0.0101] (>= 0x38D1) in bits[31:16]; fp16 storage puts
// scales[1] there (fp16 in [0x0680, 0x2150]).
static __device__ __forceinline__ bool sz_is_f32(const void* sc) {
  unsigned w0 = ((const unsigned*)sc)[0];
  return ((w0 >> 16) & 0x7fffu) >= 0x3000u;
}
static __device__ __forceinline__ float load_sz(const void* p, int i, bool f32) {
  return f32 ? ((const float*)p)[i] : __half2float(((const __half*)p)[i]);
}

// ---------------- kernel 1: x fp32 -> bf16 ----------------
__global__ void qlora_conv_x(const float4* __restrict__ x, ushort4* __restrict__ xb) {
  unsigned i = blockIdx.x * 256u + threadIdx.x;   // one float4 per thread, exact grid
  float4 a = x[i];
  ushort4 o;
  o.x = f2bf(a.x); o.y = f2bf(a.y); o.z = f2bf(a.z); o.w = f2bf(a.w);
  xb[i] = o;
}

// ---------------- kernel 2: dequant + fold LoRA -> W_eff bf16 [N][K] ----------------
__global__ void qlora_weff(const int* __restrict__ qw, const void* __restrict__ sc,
                           const void* __restrict__ zr, const float* __restrict__ lA,
                           const float* __restrict__ lB, ushort2* __restrict__ weff) {
  const int o = blockIdx.x;
  const bool f32 = sz_is_f32(sc);
  const float s = load_sz(sc, o, f32);
  const float z = load_sz(zr, o, f32);
  float b[16];
#pragma unroll
  for (int r = 0; r < 16; ++r) b[r] = lB[o * 16 + r] * 2.0f;  // SCALING = 32/16
  const int* qrow = qw + (size_t)o * (KDIM / 2);
  ushort2* wrow = weff + (size_t)o * (KDIM / 2);
  for (int i2 = threadIdx.x; i2 < KDIM / 2; i2 += 256) {
    int q = qrow[i2];
    float acc0 = 0.f, acc1 = 0.f;
#pragma unroll
    for (int r = 0; r < 16; ++r) {
      float2 a = ((const float2*)(lA + (size_t)r * KDIM))[i2];
      acc0 += b[r] * a.x;
      acc1 += b[r] * a.y;
    }
    // high nibble -> even col, low nibble -> odd col
    float w0 = (float)((q >> 4) & 15) * s + z + acc0;
    float w1 = (float)(q & 15) * s + z + acc1;
    ushort2 pk; pk.x = f2bf(w0); pk.y = f2bf(w1);
    wrow[i2] = pk;
  }
}

// ---------------- kernel 3: bf16 MFMA GEMM, C[M][N] = A[M][K] * B[N][K]^T ----------------
#define BM 128
#define BN 128
#define BK 64

__global__ __launch_bounds__(256) void qlora_gemm(const u16* __restrict__ A,
                                                  const u16* __restrict__ B,
                                                  float* __restrict__ C) {
  __shared__ __align__(16) u16 As[BM * BK];
  __shared__ __align__(16) u16 Bs[BN * BK];
  const int t = threadIdx.x;
  const int lane = t & 63;
  const int wave = t >> 6;
  const int wr = wave >> 1, wc = wave & 1;   // 2x2 wave grid, each wave owns 64x64
  const int lrow = lane & 15;                // fragment row/col within 16x16
  const int lko = (lane >> 4) * 8;           // fragment K offset (elements)
  const int brow = blockIdx.x * BM;
  const int bcol = blockIdx.y * BN;

  f32x4 acc[4][4] = {};

  const u16* gA = A + (size_t)brow * KDIM;
  const u16* gB = B + (size_t)bcol * KDIM;

  for (int kt = 0; kt < KDIM; kt += BK) {
    __syncthreads();
#pragma unroll
    for (int it = 0; it < 4; ++it) {
      int ee = it * 256 + t;
      int r = ee >> 3, c = (ee & 7) * 8;
      __builtin_amdgcn_global_load_lds(
          (const __attribute__((address_space(1))) void*)(gA + (size_t)r * KDIM + kt + c),
          (__attribute__((address_space(3))) void*)(As + ee * 8), 16, 0, 0);
    }
#pragma unroll
    for (int it = 0; it < 4; ++it) {
      int ee = it * 256 + t;
      int r = ee >> 3, c = (ee & 7) * 8;
      __builtin_amdgcn_global_load_lds(
          (const __attribute__((address_space(1))) void*)(gB + (size_t)r * KDIM + kt + c),
          (__attribute__((address_space(3))) void*)(Bs + ee * 8), 16, 0, 0);
    }
    __syncthreads();
#pragma unroll
    for (int kk = 0; kk < 2; ++kk) {
      bf16x8 af[4], bfr[4];
#pragma unroll
      for (int i = 0; i < 4; ++i)
        af[i] = *(const bf16x8*)(As + (wr * 64 + i * 16 + lrow) * BK + kk * 32 + lko);
#pragma unroll
      for (int j = 0; j < 4; ++j)
        bfr[j] = *(const bf16x8*)(Bs + (wc * 64 + j * 16 + lrow) * BK + kk * 32 + lko);
#pragma unroll
      for (int i = 0; i < 4; ++i)
#pragma unroll
        for (int j = 0; j < 4; ++j)
          acc[i][j] = __builtin_amdgcn_mfma_f32_16x16x32_bf16(af[i], bfr[j], acc[i][j], 0, 0, 0);
    }
  }

  // C/D layout: col = lane&15, row = (lane>>4)*4 + reg
  const int r0 = brow + wr * 64 + (lane >> 4) * 4;
  const int c0 = bcol + wc * 64 + lrow;
#pragma unroll
  for (int i = 0; i < 4; ++i)
#pragma unroll
    for (int j = 0; j < 4; ++j)
#pragma unroll
      for (int q = 0; q < 4; ++q)
        C[(size_t)(r0 + i * 16 + q) * NDIM + (c0 + j * 16)] = acc[i][j][q];
}

// ---------------- fallback: fp32 tiled GEMM with on-the-fly dequant (no ws) ----------------
__global__ void qlora_fallback(const float* __restrict__ X, const int* __restrict__ qw,
                               const void* __restrict__ sc, const void* __restrict__ zr,
                               const float* __restrict__ lA, const float* __restrict__ lB,
                               float* __restrict__ C) {
  __shared__ float Xs[32][65];
  __shared__ float Ws[32][65];
  const int t = threadIdx.x;
  const bool f32 = sz_is_f32(sc);
  const int brow = blockIdx.x * 64, bcol = blockIdx.y * 64;
  const int tr = t >> 4, tc = t & 15;
  float acc[4][4] = {};
  for (int k0 = 0; k0 < KDIM; k0 += 32) {
    __syncthreads();
    {
      int row = t >> 2;
      int kk0 = (t & 3) * 8;
      const float* src = X + (size_t)(brow + row) * KDIM + k0 + kk0;
#pragma unroll
      for (int u = 0; u < 8; ++u) Xs[kk0 + u][row] = src[u];
    }
    {
      int o = t >> 2;
      int kk0 = (t & 3) * 8;
      int oo = bcol + o;
      float s = load_sz(sc, oo, f32), z = load_sz(zr, oo, f32);
      const int* qrow = qw + (size_t)oo * (KDIM / 2) + (k0 + kk0) / 2;
#pragma unroll
      for (int u = 0; u < 4; ++u) {
        int q = qrow[u];
        int kk = kk0 + u * 2;
        float l0 = 0.f, l1 = 0.f;
#pragma unroll
        for (int r = 0; r < 16; ++r) {
          float br = lB[oo * 16 + r] * 2.0f;
          l0 += br * lA[(size_t)r * KDIM + k0 + kk];
          l1 += br * lA[(size_t)r * KDIM + k0 + kk + 1];
        }
        Ws[kk][o] = (float)((q >> 4) & 15) * s + z + l0;
        Ws[kk + 1][o] = (float)(q & 15) * s + z + l1;
      }
    }
    __syncthreads();
#pragma unroll
    for (int k = 0; k < 32; ++k) {
      float xv[4], wv[4];
#pragma unroll
      for (int i = 0; i < 4; ++i) xv[i] = Xs[k][tr * 4 + i];
#pragma unroll
      for (int j = 0; j < 4; ++j) wv[j] = Ws[k][tc * 4 + j];
#pragma unroll
      for (int i = 0; i < 4; ++i)
#pragma unroll
        for (int j = 0; j < 4; ++j) acc[i][j] += xv[i] * wv[j];
    }
  }
#pragma unroll
  for (int i = 0; i < 4; ++i)
#pragma unroll
    for (int j = 0; j < 4; ++j)
      C[(size_t)(brow + tr * 4 + i) * NDIM + bcol + tc * 4 + j] = acc[i][j];
}

extern "C" void kernel_launch(void* const* d_in, const int* in_sizes, int n_in,
                              void* d_out, int out_size, void* d_ws, size_t ws_size,
                              hipStream_t stream) {
  const float* x = (const float*)d_in[0];
  const int* qw = (const int*)d_in[1];
  const void* sc = d_in[2];
  const void* zr = d_in[3];
  const float* lA = (const float*)d_in[4];
  const float* lB = (const float*)d_in[5];
  float* out = (float*)d_out;

  const size_t xb_bytes = (size_t)MDIM * KDIM * 2;
  const size_t weff_bytes = (size_t)NDIM * KDIM * 2;
  if (ws_size >= xb_bytes + weff_bytes) {
    u16* xb = (u16*)d_ws;
    u16* weff = xb + (size_t)MDIM * KDIM;
    qlora_conv_x<<<(MDIM * KDIM / 4) / 256, 256, 0, stream>>>((const float4*)x, (ushort4*)xb);
    qlora_weff<<<NDIM, 256, 0, stream>>>(qw, sc, zr, lA, lB, (ushort2*)weff);
    dim3 grid(MDIM / BM, NDIM / BN);
    qlora_gemm<<<grid, 256, 0, stream>>>(xb, weff, out);
  } else {
    dim3 grid(MDIM / 64, NDIM / 64);
    qlora_fallback<<<grid, 256, 0, stream>>>(x, qw, sc, zr, lA, lB, out);
  }
}

// Round 3
// 341.987 us; speedup vs baseline: 1.4047x; 1.4047x over previous
//
#include <hip/hip_runtime.h>
#include <hip/hip_fp16.h>

#define MDIM 8192   // B*S = 4*2048
#define NDIM 4096   // OUT
#define KDIM 4096   // IN

typedef unsigned short u16;
typedef __bf16 bf16x8 __attribute__((ext_vector_type(8)));
typedef float f32x4 __attribute__((ext_vector_type(4)));

static __device__ __forceinline__ u16 f2bf(float f) {
  union { float f; unsigned u; } v; v.f = f;
  unsigned r = v.u + 0x7fffu + ((v.u >> 16) & 1u);  // round-to-nearest-even
  return (u16)(r >> 16);
}

// scales/zeros may arrive as fp16 (reference dtype) or promoted to fp32.
static __device__ __forceinline__ bool sz_is_f32(const void* sc) {
  unsigned w0 = ((const unsigned*)sc)[0];
  return ((w0 >> 16) & 0x7fffu) >= 0x3000u;
}
static __device__ __forceinline__ float load_sz(const void* p, int i, bool f32) {
  return f32 ? ((const float*)p)[i] : __half2float(((const __half*)p)[i]);
}

// ---------------- kernel 1: x fp32 -> bf16 ----------------
__global__ void qlora_conv_x(const float4* __restrict__ x, ushort4* __restrict__ xb) {
  unsigned i = blockIdx.x * 256u + threadIdx.x;
  float4 a = x[i];
  ushort4 o;
  o.x = f2bf(a.x); o.y = f2bf(a.y); o.z = f2bf(a.z); o.w = f2bf(a.w);
  xb[i] = o;
}

// ---------------- kernel 2: dequant + fold LoRA -> W_eff bf16 [N][K] ----------------
__global__ void qlora_weff(const int* __restrict__ qw, const void* __restrict__ sc,
                           const void* __restrict__ zr, const float* __restrict__ lA,
                           const float* __restrict__ lB, ushort2* __restrict__ weff) {
  const int o = blockIdx.x;
  const bool f32 = sz_is_f32(sc);
  const float s = load_sz(sc, o, f32);
  const float z = load_sz(zr, o, f32);
  float b[16];
#pragma unroll
  for (int r = 0; r < 16; ++r) b[r] = lB[o * 16 + r] * 2.0f;  // SCALING = 32/16
  const int* qrow = qw + (size_t)o * (KDIM / 2);
  ushort2* wrow = weff + (size_t)o * (KDIM / 2);
  for (int i2 = threadIdx.x; i2 < KDIM / 2; i2 += 256) {
    int q = qrow[i2];
    float acc0 = 0.f, acc1 = 0.f;
#pragma unroll
    for (int r = 0; r < 16; ++r) {
      float2 a = ((const float2*)(lA + (size_t)r * KDIM))[i2];
      acc0 += b[r] * a.x;
      acc1 += b[r] * a.y;
    }
    float w0 = (float)((q >> 4) & 15) * s + z + acc0;   // high nibble -> even col
    float w1 = (float)(q & 15) * s + z + acc1;          // low nibble -> odd col
    ushort2 pk; pk.x = f2bf(w0); pk.y = f2bf(w1);
    wrow[i2] = pk;
  }
}

// ---------------- kernel 3: 256x256 8-phase bf16 MFMA GEMM ----------------
// C[M][N] = A[M][K] * B[N][K]^T.  8 waves (2Mx4N), BK=64, LDS 128KiB dbuf,
// XOR-swizzle (granule ^= row&7), counted vmcnt(2) at phases 4/8.

// stage one half-tile (128 rows x 64 K) : 2 global_load_lds per thread.
// SB = per-thread pre-swizzled source base, REGOFF = 0 (A) or 16384 (B) u16.
#define STAGE(SB, BUFSEL, REGOFF, HALF, KT) do {                                   \
    const u16* _s0 = (SB) + (size_t)(HALF) * (128 * (size_t)KDIM) + (KT) * 64;     \
    u16* _d0 = lds + (BUFSEL) * 32768 + (REGOFF) + (HALF) * 8192 + wave * 1024;    \
    __builtin_amdgcn_global_load_lds(                                              \
        (const __attribute__((address_space(1))) void*)_s0,                        \
        (__attribute__((address_space(3))) void*)_d0, 16, 0, 0);                   \
    __builtin_amdgcn_global_load_lds(                                              \
        (const __attribute__((address_space(1))) void*)(_s0 + 8 * KDIM),           \
        (__attribute__((address_space(3))) void*)(_d0 + 512), 16, 0, 0);           \
  } while (0)

#define VMW2 asm volatile("s_waitcnt vmcnt(2)" ::: "memory")

// one phase: (BUF, QM, KK); LOADB: also load B-frags for this KK into bfr[.][KK]
#define PHASE(BUF, QM, KK, LOADB, STAGE_STMT, VM_STMT) do {                        \
    __builtin_amdgcn_sched_barrier(0);                                            \
    bf16x8 af[4];                                                                 \
    {                                                                             \
      int _ab = (BUF) * 32768 + (QM) * 8192 + aRowBase;                           \
      if (KK) _ab ^= 32;                                                          \
      _Pragma("unroll")                                                           \
      for (int mf = 0; mf < 4; ++mf)                                              \
        af[mf] = *(const bf16x8*)(lds + (_ab + mf * 1024));                       \
      if (LOADB) {                                                                \
        int _bb = (BUF) * 32768 + bRowBase;                                       \
        if (KK) _bb ^= 32;                                                        \
        _Pragma("unroll")                                                         \
        for (int nf = 0; nf < 4; ++nf)                                            \
          bfr[nf][KK] = *(const bf16x8*)(lds + (_bb + nf * 1024));                \
      }                                                                           \
    }                                                                             \
    STAGE_STMT;                                                                   \
    __builtin_amdgcn_sched_barrier(0);                                            \
    __builtin_amdgcn_s_barrier();                                                 \
    asm volatile("s_waitcnt lgkmcnt(0)" ::: "memory");                            \
    __builtin_amdgcn_sched_barrier(0);                                            \
    __builtin_amdgcn_s_setprio(1);                                                \
    _Pragma("unroll")                                                             \
    for (int mf = 0; mf < 4; ++mf)                                                \
      _Pragma("unroll")                                                           \
      for (int nf = 0; nf < 4; ++nf)                                              \
        acc[QM][mf][nf] = __builtin_amdgcn_mfma_f32_16x16x32_bf16(                \
            af[mf], bfr[nf][KK], acc[QM][mf][nf], 0, 0, 0);                       \
    __builtin_amdgcn_s_setprio(0);                                                \
    VM_STMT;                                                                      \
    __builtin_amdgcn_sched_barrier(0);                                            \
    __builtin_amdgcn_s_barrier();                                                 \
  } while (0)

__global__ __launch_bounds__(512, 2) void qlora_gemm8p(const u16* __restrict__ A,
                                                       const u16* __restrict__ B,
                                                       float* __restrict__ C) {
  __shared__ __align__(16) u16 lds[65536];  // 128 KiB: buf{0,1} x (A 32KB + B 32KB)

  const int t = threadIdx.x;
  const int lane = t & 63;
  const int wave = t >> 6;          // 0..7
  const int wr = wave >> 2;         // 0..1  (M)
  const int wc = wave & 3;          // 0..3  (N)
  const int lrow = lane & 15;
  const int khalf = lane >> 4;      // 0..3
  const int lr7 = lane & 7;
  const int g0 = (khalf ^ lr7) * 8; // swizzled granule (u16 units)

  // XCD-aware bijective swizzle of the 512-block grid (64 blocks per XCD).
  const int flat = blockIdx.x;
  const int swz = (flat & 7) * 64 + (flat >> 3);
  const int brow = (swz & 31) * 256;   // M-tile
  const int bcol = (swz >> 5) * 256;   // N-tile

  // per-thread LDS read bases (u16 units), swizzle g0 folded in
  const int aRowBase = (wr * 64 + lrow) * 64 + g0;
  const int bRowBase = 16384 + (wc * 64 + lrow) * 64 + g0;

  // per-thread pre-swizzled global staging bases:
  // row = wave*16 + L*8 + (lane>>3), granule = (lane&7) ^ ((lane>>3)&7)
  const int srow = wave * 16 + (lane >> 3);
  const int sg = ((lane & 7) ^ ((lane >> 3) & 7)) * 8;
  const u16* aS = A + (size_t)(brow + srow) * KDIM + sg;
  const u16* bS = B + (size_t)(bcol + srow) * KDIM + sg;

  f32x4 acc[2][4][4] = {};
  bf16x8 bfr[4][2];

  // ---- prologue: kt0 (4 halves -> buf0) + A0(kt1) -> buf1 ----
  STAGE(aS, 0, 0, 0, 0);
  STAGE(aS, 0, 0, 1, 0);
  STAGE(bS, 0, 16384, 0, 0);
  STAGE(bS, 0, 16384, 1, 0);
  STAGE(aS, 1, 0, 0, 1);
  asm volatile("s_waitcnt vmcnt(2)" ::: "memory");
  __builtin_amdgcn_s_barrier();

#pragma unroll 1
  for (int it = 0; it < KDIM / 128; ++it) {
    const int o1 = 2 * it + 1;
    const int e2 = (2 * it + 2) & 63;
    const int o3 = (2 * it + 3) & 63;
    PHASE(0, 0, 0, 1, STAGE(aS, 1, 0, 1, o1), );       // P1: A1(o1)->buf1
    PHASE(0, 0, 1, 1, STAGE(bS, 1, 16384, 0, o1), );   // P2: B0(o1)->buf1
    PHASE(0, 1, 0, 0, STAGE(bS, 1, 16384, 1, o1), );   // P3: B1(o1)->buf1
    PHASE(0, 1, 1, 0, STAGE(aS, 0, 0, 0, e2), VMW2);   // P4: A0(e2)->buf0
    PHASE(1, 0, 0, 1, STAGE(aS, 0, 0, 1, e2), );       // P5: A1(e2)->buf0
    PHASE(1, 0, 1, 1, STAGE(bS, 0, 16384, 0, e2), );   // P6: B0(e2)->buf0
    PHASE(1, 1, 0, 0, STAGE(bS, 0, 16384, 1, e2), );   // P7: B1(e2)->buf0
    PHASE(1, 1, 1, 0, STAGE(aS, 1, 0, 0, o3), VMW2);   // P8: A0(o3)->buf1
  }

  asm volatile("s_waitcnt vmcnt(0) lgkmcnt(0)" ::: "memory");

  // ---- epilogue: C/D layout col=lane&15, row=(lane>>4)*4+q ----
  float* Cb = C + (size_t)brow * NDIM + bcol;
  const int rb = wr * 64 + (lane >> 4) * 4;
  const int cb = wc * 64 + lrow;
#pragma unroll
  for (int qm = 0; qm < 2; ++qm)
#pragma unroll
    for (int mf = 0; mf < 4; ++mf)
#pragma unroll
      for (int nf = 0; nf < 4; ++nf) {
        const int r = qm * 128 + rb + mf * 16;
        const int c = cb + nf * 16;
        f32x4 v = acc[qm][mf][nf];
#pragma unroll
        for (int q = 0; q < 4; ++q)
          Cb[(size_t)(r + q) * NDIM + c] = v[q];
      }
}

// ---------------- fallback: fp32 tiled GEMM with on-the-fly dequant (no ws) ----------------
__global__ void qlora_fallback(const float* __restrict__ X, const int* __restrict__ qw,
                               const void* __restrict__ sc, const void* __restrict__ zr,
                               const float* __restrict__ lA, const float* __restrict__ lB,
                               float* __restrict__ C) {
  __shared__ float Xs[32][65];
  __shared__ float Ws[32][65];
  const int t = threadIdx.x;
  const bool f32 = sz_is_f32(sc);
  const int brow = blockIdx.x * 64, bcol = blockIdx.y * 64;
  const int tr = t >> 4, tc = t & 15;
  float acc[4][4] = {};
  for (int k0 = 0; k0 < KDIM; k0 += 32) {
    __syncthreads();
    {
      int row = t >> 2;
      int kk0 = (t & 3) * 8;
      const float* src = X + (size_t)(brow + row) * KDIM + k0 + kk0;
#pragma unroll
      for (int u = 0; u < 8; ++u) Xs[kk0 + u][row] = src[u];
    }
    {
      int o = t >> 2;
      int kk0 = (t & 3) * 8;
      int oo = bcol + o;
      float s = load_sz(sc, oo, f32), z = load_sz(zr, oo, f32);
      const int* qrow = qw + (size_t)oo * (KDIM / 2) + (k0 + kk0) / 2;
#pragma unroll
      for (int u = 0; u < 4; ++u) {
        int q = qrow[u];
        int kk = kk0 + u * 2;
        float l0 = 0.f, l1 = 0.f;
#pragma unroll
        for (int r = 0; r < 16; ++r) {
          float br = lB[oo * 16 + r] * 2.0f;
          l0 += br * lA[(size_t)r * KDIM + k0 + kk];
          l1 += br * lA[(size_t)r * KDIM + k0 + kk + 1];
        }
        Ws[kk][o] = (float)((q >> 4) & 15) * s + z + l0;
        Ws[kk + 1][o] = (float)(q & 15) * s + z + l1;
      }
    }
    __syncthreads();
#pragma unroll
    for (int k = 0; k < 32; ++k) {
      float xv[4], wv[4];
#pragma unroll
      for (int i = 0; i < 4; ++i) xv[i] = Xs[k][tr * 4 + i];
#pragma unroll
      for (int j = 0; j < 4; ++j) wv[j] = Ws[k][tc * 4 + j];
#pragma unroll
      for (int i = 0; i < 4; ++i)
#pragma unroll
        for (int j = 0; j < 4; ++j) acc[i][j] += xv[i] * wv[j];
    }
  }
#pragma unroll
  for (int i = 0; i < 4; ++i)
#pragma unroll
    for (int j = 0; j < 4; ++j)
      C[(size_t)(brow + tr * 4 + i) * NDIM + bcol + tc * 4 + j] = acc[i][j];
}

extern "C" void kernel_launch(void* const* d_in, const int* in_sizes, int n_in,
                              void* d_out, int out_size, void* d_ws, size_t ws_size,
                              hipStream_t stream) {
  const float* x = (const float*)d_in[0];
  const int* qw = (const int*)d_in[1];
  const void* sc = d_in[2];
  const void* zr = d_in[3];
  const float* lA = (const float*)d_in[4];
  const float* lB = (const float*)d_in[5];
  float* out = (float*)d_out;

  const size_t xb_bytes = (size_t)MDIM * KDIM * 2;
  const size_t weff_bytes = (size_t)NDIM * KDIM * 2;
  if (ws_size >= xb_bytes + weff_bytes) {
    u16* xb = (u16*)d_ws;
    u16* weff = xb + (size_t)MDIM * KDIM;
    qlora_conv_x<<<(MDIM * KDIM / 4) / 256, 256, 0, stream>>>((const float4*)x, (ushort4*)xb);
    qlora_weff<<<NDIM, 256, 0, stream>>>(qw, sc, zr, lA, lB, (ushort2*)weff);
    dim3 grid((MDIM / 256) * (NDIM / 256));  // 512 blocks
    qlora_gemm8p<<<grid, 512, 0, stream>>>(xb, weff, out);
  } else {
    dim3 grid(MDIM / 64, NDIM / 64);
    qlora_fallback<<<grid, 256, 0, stream>>>(x, qw, sc, zr, lA, lB, out);
  }
}

// Round 4
// 341.251 us; speedup vs baseline: 1.4077x; 1.0022x over previous
//
#include <hip/hip_runtime.h>
#include <hip/hip_fp16.h>

#define MDIM 8192   // B*S = 4*2048
#define NDIM 4096   // OUT
#define KDIM 4096   // IN

typedef unsigned short u16;
typedef __bf16 bf16x8 __attribute__((ext_vector_type(8)));
typedef float f32x4 __attribute__((ext_vector_type(4)));

static __device__ __forceinline__ u16 f2bf(float f) {
  union { float f; unsigned u; } v; v.f = f;
  unsigned r = v.u + 0x7fffu + ((v.u >> 16) & 1u);  // round-to-nearest-even
  return (u16)(r >> 16);
}

// scales/zeros may arrive as fp16 (reference dtype) or promoted to fp32.
static __device__ __forceinline__ bool sz_is_f32(const void* sc) {
  unsigned w0 = ((const unsigned*)sc)[0];
  return ((w0 >> 16) & 0x7fffu) >= 0x3000u;
}
static __device__ __forceinline__ float load_sz(const void* p, int i, bool f32) {
  return f32 ? ((const float*)p)[i] : __half2float(((const __half*)p)[i]);
}

// ---------------- kernel 1: fused {x fp32->bf16} + {dequant+LoRA-fold W_eff} ----------------
#define CONVB 2048
__global__ void qlora_prep(const float4* __restrict__ x, ushort4* __restrict__ xb,
                           const int* __restrict__ qw, const void* __restrict__ sc,
                           const void* __restrict__ zr, const float* __restrict__ lA,
                           const float* __restrict__ lB, ushort2* __restrict__ weff) {
  if (blockIdx.x < CONVB) {
    // conv: MDIM*KDIM/4 = 8388608 float4; 2048 blocks x 256 thr x 16
    unsigned base = blockIdx.x * 256u + threadIdx.x;
#pragma unroll
    for (int s = 0; s < 16; ++s) {
      unsigned i = base + (unsigned)s * (CONVB * 256u);
      float4 a = x[i];
      ushort4 o;
      o.x = f2bf(a.x); o.y = f2bf(a.y); o.z = f2bf(a.z); o.w = f2bf(a.w);
      xb[i] = o;
    }
  } else {
    const int o = blockIdx.x - CONVB;
    const bool f32 = sz_is_f32(sc);
    const float s = load_sz(sc, o, f32);
    const float z = load_sz(zr, o, f32);
    float b[16];
#pragma unroll
    for (int r = 0; r < 16; ++r) b[r] = lB[o * 16 + r] * 2.0f;  // SCALING = 32/16
    const int* qrow = qw + (size_t)o * (KDIM / 2);
    ushort2* wrow = weff + (size_t)o * (KDIM / 2);
    for (int i2 = threadIdx.x; i2 < KDIM / 2; i2 += 256) {
      int q = qrow[i2];
      float acc0 = 0.f, acc1 = 0.f;
#pragma unroll
      for (int r = 0; r < 16; ++r) {
        float2 a = ((const float2*)(lA + (size_t)r * KDIM))[i2];
        acc0 += b[r] * a.x;
        acc1 += b[r] * a.y;
      }
      float w0 = (float)((q >> 4) & 15) * s + z + acc0;   // high nibble -> even col
      float w1 = (float)(q & 15) * s + z + acc1;          // low nibble -> odd col
      ushort2 pk; pk.x = f2bf(w0); pk.y = f2bf(w1);
      wrow[i2] = pk;
    }
  }
}

// ---------------- kernel 2: 256x256 bf16 MFMA GEMM, pipelined 2-barrier K-tile ----------------
// C[M][N] = A[M][K] * B[N][K]^T. 8 waves (2Mx4N), BK=64, LDS 128KiB dbuf,
// XOR-swizzle (granule ^= row&7). Per K-tile: vmcnt(2)+bar, R0R1 | MFMA0 | vmcnt(6)+bar,
// R2|MFMA1, R3|MFMA2, MFMA3 — ds_reads overlap MFMA on separate pipes.

#define STAGE(SB, BUFSEL, REGOFF, HALF, KT) do {                                   \
    const u16* _s0 = (SB) + (size_t)(HALF) * (128 * (size_t)KDIM) + (KT) * 64;     \
    u16* _d0 = lds + (BUFSEL) * 32768 + (REGOFF) + (HALF) * 8192 + wave * 1024;    \
    __builtin_amdgcn_global_load_lds(                                              \
        (const __attribute__((address_space(1))) void*)_s0,                        \
        (__attribute__((address_space(3))) void*)_d0, 16, 0, 0);                   \
    __builtin_amdgcn_global_load_lds(                                              \
        (const __attribute__((address_space(1))) void*)(_s0 + 8 * KDIM),           \
        (__attribute__((address_space(3))) void*)(_d0 + 512), 16, 0, 0);           \
  } while (0)

#define SBAR0 __builtin_amdgcn_sched_barrier(0)

__global__ __launch_bounds__(512, 2) void qlora_gemm_p(const u16* __restrict__ A,
                                                       const u16* __restrict__ B,
                                                       float* __restrict__ C) {
  __shared__ __align__(16) u16 lds[65536];  // 128 KiB: buf{0,1} x (A 32KB + B 32KB)

  const int t = threadIdx.x;
  const int lane = t & 63;
  const int wave = t >> 6;          // 0..7
  const int wr = wave >> 2;         // 0..1  (M)
  const int wc = wave & 3;          // 0..3  (N)
  const int lrow = lane & 15;
  const int khalf = lane >> 4;      // 0..3
  const int g0 = (khalf ^ (lane & 7)) * 8;  // swizzled granule (u16 units)

  // XCD-aware bijective swizzle of the 512-block grid (64 blocks per XCD).
  const int flat = blockIdx.x;
  const int swz = (flat & 7) * 64 + (flat >> 3);
  const int brow = (swz & 31) * 256;   // M-tile
  const int bcol = (swz >> 5) * 256;   // N-tile

  const int aRowBase = (wr * 64 + lrow) * 64 + g0;            // u16 units
  const int bRowBase = 16384 + (wc * 64 + lrow) * 64 + g0;

  // per-thread pre-swizzled global staging base:
  // row = wave*16 + L*8 + (lane>>3), granule = (lane&7) ^ ((lane>>3)&7)
  const int srow = wave * 16 + (lane >> 3);
  const int sg = ((lane & 7) ^ ((lane >> 3) & 7)) * 8;
  const u16* aS = A + (size_t)(brow + srow) * KDIM + sg;
  const u16* bS = B + (size_t)(bcol + srow) * KDIM + sg;

  f32x4 acc[2][4][4] = {};

  // prologue: stage kt0 in issue-order [A0, B0, B1, A1] -> buf0
  STAGE(aS, 0, 0, 0, 0);
  STAGE(bS, 0, 16384, 0, 0);
  STAGE(bS, 0, 16384, 1, 0);
  STAGE(aS, 0, 0, 1, 0);

#pragma unroll 1
  for (int it = 0; it < KDIM / 64; ++it) {
    const int buf = it & 1;
    const int nbuf = buf ^ 1;
    const int nxt = (it + 1) & 63;
    const int abase = buf * 32768;

    // ---- top gate: own A0,B0,B1(kt) arrived (A1 may be in flight) ----
    asm volatile("s_waitcnt vmcnt(2)" ::: "memory");
    SBAR0;
    __builtin_amdgcn_s_barrier();
    SBAR0;

    // R0: A(QM0,KK0) + B(KK0);  R1: A(QM0,KK1) + B(KK1)
    bf16x8 af0[4], af1[4], bfr0[4], bfr1[4];
#pragma unroll
    for (int mf = 0; mf < 4; ++mf)
      af0[mf] = *(const bf16x8*)(lds + (abase + aRowBase + mf * 1024));
#pragma unroll
    for (int nf = 0; nf < 4; ++nf)
      bfr0[nf] = *(const bf16x8*)(lds + (abase + bRowBase + nf * 1024));
#pragma unroll
    for (int mf = 0; mf < 4; ++mf)
      af1[mf] = *(const bf16x8*)(lds + ((abase + aRowBase + mf * 1024) ^ 32));
#pragma unroll
    for (int nf = 0; nf < 4; ++nf)
      bfr1[nf] = *(const bf16x8*)(lds + ((abase + bRowBase + nf * 1024) ^ 32));
    SBAR0;
    STAGE(aS, nbuf, 0, 0, nxt);        // A0(kt+1)
    STAGE(bS, nbuf, 16384, 0, nxt);    // B0(kt+1)
    SBAR0;

    // MFMA cluster 0: acc[0] += af0 x bfr0
    __builtin_amdgcn_s_setprio(1);
#pragma unroll
    for (int mf = 0; mf < 4; ++mf)
#pragma unroll
      for (int nf = 0; nf < 4; ++nf)
        acc[0][mf][nf] = __builtin_amdgcn_mfma_f32_16x16x32_bf16(af0[mf], bfr0[nf], acc[0][mf][nf], 0, 0, 0);
    __builtin_amdgcn_s_setprio(0);
    SBAR0;
    STAGE(bS, nbuf, 16384, 1, nxt);    // B1(kt+1)
    SBAR0;

    // ---- mid gate: everyone's A1(kt) arrived; kt+1's A0,B0,B1 stay in flight ----
    asm volatile("s_waitcnt vmcnt(6)" ::: "memory");
    SBAR0;
    __builtin_amdgcn_s_barrier();
    SBAR0;

    // R2: A(QM1,KK0)
    bf16x8 af2[4], af3[4];
#pragma unroll
    for (int mf = 0; mf < 4; ++mf)
      af2[mf] = *(const bf16x8*)(lds + (abase + 8192 + aRowBase + mf * 1024));
    SBAR0;

    // MFMA cluster 1: acc[0] += af1 x bfr1
    __builtin_amdgcn_s_setprio(1);
#pragma unroll
    for (int mf = 0; mf < 4; ++mf)
#pragma unroll
      for (int nf = 0; nf < 4; ++nf)
        acc[0][mf][nf] = __builtin_amdgcn_mfma_f32_16x16x32_bf16(af1[mf], bfr1[nf], acc[0][mf][nf], 0, 0, 0);
    __builtin_amdgcn_s_setprio(0);
    SBAR0;

    // R3: A(QM1,KK1); stage A1(kt+1)
#pragma unroll
    for (int mf = 0; mf < 4; ++mf)
      af3[mf] = *(const bf16x8*)(lds + ((abase + 8192 + aRowBase + mf * 1024) ^ 32));
    STAGE(aS, nbuf, 0, 1, nxt);        // A1(kt+1)
    SBAR0;

    // MFMA cluster 2: acc[1] += af2 x bfr0
    __builtin_amdgcn_s_setprio(1);
#pragma unroll
    for (int mf = 0; mf < 4; ++mf)
#pragma unroll
      for (int nf = 0; nf < 4; ++nf)
        acc[1][mf][nf] = __builtin_amdgcn_mfma_f32_16x16x32_bf16(af2[mf], bfr0[nf], acc[1][mf][nf], 0, 0, 0);
    __builtin_amdgcn_s_setprio(0);
    SBAR0;

    // MFMA cluster 3: acc[1] += af3 x bfr1
    __builtin_amdgcn_s_setprio(1);
#pragma unroll
    for (int mf = 0; mf < 4; ++mf)
#pragma unroll
      for (int nf = 0; nf < 4; ++nf)
        acc[1][mf][nf] = __builtin_amdgcn_mfma_f32_16x16x32_bf16(af3[mf], bfr1[nf], acc[1][mf][nf], 0, 0, 0);
    __builtin_amdgcn_s_setprio(0);
    SBAR0;
  }

  asm volatile("s_waitcnt vmcnt(0) lgkmcnt(0)" ::: "memory");

  // epilogue: C/D layout col=lane&15, row=(lane>>4)*4+q
  float* Cb = C + (size_t)brow * NDIM + bcol;
  const int rb = wr * 64 + (lane >> 4) * 4;
  const int cb = wc * 64 + lrow;
#pragma unroll
  for (int qm = 0; qm < 2; ++qm)
#pragma unroll
    for (int mf = 0; mf < 4; ++mf)
#pragma unroll
      for (int nf = 0; nf < 4; ++nf) {
        const int r = qm * 128 + rb + mf * 16;
        const int c = cb + nf * 16;
        f32x4 v = acc[qm][mf][nf];
#pragma unroll
        for (int q = 0; q < 4; ++q)
          Cb[(size_t)(r + q) * NDIM + c] = v[q];
      }
}

// ---------------- fallback: fp32 tiled GEMM with on-the-fly dequant (no ws) ----------------
__global__ void qlora_fallback(const float* __restrict__ X, const int* __restrict__ qw,
                               const void* __restrict__ sc, const void* __restrict__ zr,
                               const float* __restrict__ lA, const float* __restrict__ lB,
                               float* __restrict__ C) {
  __shared__ float Xs[32][65];
  __shared__ float Ws[32][65];
  const int t = threadIdx.x;
  const bool f32 = sz_is_f32(sc);
  const int brow = blockIdx.x * 64, bcol = blockIdx.y * 64;
  const int tr = t >> 4, tc = t & 15;
  float acc[4][4] = {};
  for (int k0 = 0; k0 < KDIM; k0 += 32) {
    __syncthreads();
    {
      int row = t >> 2;
      int kk0 = (t & 3) * 8;
      const float* src = X + (size_t)(brow + row) * KDIM + k0 + kk0;
#pragma unroll
      for (int u = 0; u < 8; ++u) Xs[kk0 + u][row] = src[u];
    }
    {
      int o = t >> 2;
      int kk0 = (t & 3) * 8;
      int oo = bcol + o;
      float s = load_sz(sc, oo, f32), z = load_sz(zr, oo, f32);
      const int* qrow = qw + (size_t)oo * (KDIM / 2) + (k0 + kk0) / 2;
#pragma unroll
      for (int u = 0; u < 4; ++u) {
        int q = qrow[u];
        int kk = kk0 + u * 2;
        float l0 = 0.f, l1 = 0.f;
#pragma unroll
        for (int r = 0; r < 16; ++r) {
          float br = lB[oo * 16 + r] * 2.0f;
          l0 += br * lA[(size_t)r * KDIM + k0 + kk];
          l1 += br * lA[(size_t)r * KDIM + k0 + kk + 1];
        }
        Ws[kk][o] = (float)((q >> 4) & 15) * s + z + l0;
        Ws[kk + 1][o] = (float)(q & 15) * s + z + l1;
      }
    }
    __syncthreads();
#pragma unroll
    for (int k = 0; k < 32; ++k) {
      float xv[4], wv[4];
#pragma unroll
      for (int i = 0; i < 4; ++i) xv[i] = Xs[k][tr * 4 + i];
#pragma unroll
      for (int j = 0; j < 4; ++j) wv[j] = Ws[k][tc * 4 + j];
#pragma unroll
      for (int i = 0; i < 4; ++i)
#pragma unroll
        for (int j = 0; j < 4; ++j) acc[i][j] += xv[i] * wv[j];
    }
  }
#pragma unroll
  for (int i = 0; i < 4; ++i)
#pragma unroll
    for (int j = 0; j < 4; ++j)
      C[(size_t)(brow + tr * 4 + i) * NDIM + bcol + tc * 4 + j] = acc[i][j];
}

extern "C" void kernel_launch(void* const* d_in, const int* in_sizes, int n_in,
                              void* d_out, int out_size, void* d_ws, size_t ws_size,
                              hipStream_t stream) {
  const float* x = (const float*)d_in[0];
  const int* qw = (const int*)d_in[1];
  const void* sc = d_in[2];
  const void* zr = d_in[3];
  const float* lA = (const float*)d_in[4];
  const float* lB = (const float*)d_in[5];
  float* out = (float*)d_out;

  const size_t xb_bytes = (size_t)MDIM * KDIM * 2;
  const size_t weff_bytes = (size_t)NDIM * KDIM * 2;
  if (ws_size >= xb_bytes + weff_bytes) {
    u16* xb = (u16*)d_ws;
    u16* weff = xb + (size_t)MDIM * KDIM;
    qlora_prep<<<CONVB + NDIM, 256, 0, stream>>>((const float4*)x, (ushort4*)xb,
                                                 qw, sc, zr, lA, lB, (ushort2*)weff);
    dim3 grid((MDIM / 256) * (NDIM / 256));  // 512 blocks
    qlora_gemm_p<<<grid, 512, 0, stream>>>(xb, weff, out);
  } else {
    dim3 grid(MDIM / 64, NDIM / 64);
    qlora_fallback<<<grid, 256, 0, stream>>>(x, qw, sc, zr, lA, lB, out);
  }
}